// Round 11
// baseline (359.343 us; speedup 1.0000x reference)
//
#include <hip/hip_runtime.h>
#include <cstdint>
#include <cstddef>

typedef unsigned short u16;
typedef __attribute__((ext_vector_type(8))) short bf16x8;
typedef __attribute__((ext_vector_type(4))) float f32x4;

#define MFMA32(a, b, c) __builtin_amdgcn_mfma_f32_16x16x32_bf16(a, b, c, 0, 0, 0)

__device__ __forceinline__ u16 f2b(float f) {
  union { float f; unsigned u; } v; v.f = f;
  unsigned u = v.u;
  return (u16)((u + 0x7fffu + ((u >> 16) & 1u)) >> 16);
}
__device__ __forceinline__ float b2f(u16 h) {
  union { unsigned u; float f; } v; v.u = ((unsigned)h) << 16;
  return v.f;
}

// async global->LDS, 16B per lane. LDS dest must be wave-uniform base + lane*16.
__device__ __forceinline__ void g2l16(const void* g, void* l) {
  __builtin_amdgcn_global_load_lds((__attribute__((address_space(1))) void*)(g),
                                   (__attribute__((address_space(3))) void*)(l), 16, 0, 0);
}

// ---------------- ALL fp32->bf16 casts in one launch --------------------------
__global__ __launch_bounds__(256) void cast_all(const float* __restrict__ x,
                                                const float* __restrict__ W0,
                                                const float* __restrict__ W1,
                                                const float* __restrict__ W2,
                                                const float* __restrict__ W3,
                                                const float* __restrict__ Wv,
                                                const float* __restrict__ Wo,
                                                u16* __restrict__ xb,
                                                u16* __restrict__ Wall,
                                                u16* __restrict__ Wob) {
  const int blk = blockIdx.x;
  const float* src;
  u16* dst;
  int li;
  if (blk < 8192) {
    src = x; dst = xb; li = blk * 256 + threadIdx.x;
  } else if (blk < 16384) {
    const int s = (blk - 8192) >> 11;
    src = s == 0 ? W0 : s == 1 ? W1 : s == 2 ? W2 : W3;
    dst = Wall + (size_t)s * 2097152;
    li = ((blk - 8192) & 2047) * 256 + threadIdx.x;
  } else if (blk < 20480) {
    src = Wv; dst = Wall + (size_t)4 * 2097152;
    li = (blk - 16384) * 256 + threadIdx.x;
  } else {
    src = Wo; dst = Wob;
    li = (blk - 20480) * 256 + threadIdx.x;
  }
  float4 v = ((const float4*)src)[li];
  ushort4 r;
  r.x = f2b(v.x); r.y = f2b(v.y); r.z = f2b(v.z); r.w = f2b(v.w);
  ((ushort4*)dst)[li] = r;
}

// ---------------- C = A @ B^T  128x128 tile (m97 structure; final projection) -
template <bool BF16_OUT>
__global__ __launch_bounds__(256) void gemm_bt(const u16* __restrict__ A,
                                               const u16* __restrict__ B,
                                               void* __restrict__ C, int N, int K) {
  __shared__ u16 As[128 * 64];
  __shared__ u16 Bs[128 * 64];
  const int tid = threadIdx.x;
  const int wid = tid >> 6;
  const int lane = tid & 63;
  const int lm = lane & 15;
  const int quad = lane >> 4;
  const int r3 = lm & 7;
  const int wm = (wid & 1) * 64;
  const int wn = (wid >> 1) * 64;
  const int bm = blockIdx.y * 128;
  const int bn = blockIdx.x * 128;

  const u16* Ab = A + (size_t)bm * K;
  const u16* Bb = B + (size_t)bn * K;

  f32x4 zero = {0.f, 0.f, 0.f, 0.f};
  f32x4 acc[4][4];
#pragma unroll
  for (int i = 0; i < 4; ++i)
#pragma unroll
    for (int j = 0; j < 4; ++j) acc[i][j] = zero;

  for (int k0 = 0; k0 < K; k0 += 64) {
#pragma unroll
    for (int it = 0; it < 4; ++it) {
      int c = it * 256 + tid;
      int rg = c >> 6, rw = (c >> 3) & 7, u = c & 7;
      int row = rg * 8 + rw;
      int chd = u ^ rw;
      g2l16(Ab + (size_t)row * K + k0 + chd * 8, As + c * 8);
      g2l16(Bb + (size_t)row * K + k0 + chd * 8, Bs + c * 8);
    }
    __syncthreads();
#pragma unroll
    for (int ks = 0; ks < 2; ++ks) {
      bf16x8 a[4], b[4];
      int chd = ks * 4 + quad;
#pragma unroll
      for (int i = 0; i < 4; ++i) {
        int row = wm + i * 16 + lm;
        a[i] = *(const bf16x8*)(As + (((row >> 3) * 64 + r3 * 8 + (chd ^ r3)) * 8));
      }
#pragma unroll
      for (int j = 0; j < 4; ++j) {
        int row = wn + j * 16 + lm;
        b[j] = *(const bf16x8*)(Bs + (((row >> 3) * 64 + r3 * 8 + (chd ^ r3)) * 8));
      }
#pragma unroll
      for (int i = 0; i < 4; ++i)
#pragma unroll
        for (int j = 0; j < 4; ++j)
          acc[i][j] = MFMA32(a[i], b[j], acc[i][j]);
    }
    __syncthreads();
  }

#pragma unroll
  for (int i = 0; i < 4; ++i)
#pragma unroll
    for (int j = 0; j < 4; ++j)
#pragma unroll
      for (int r = 0; r < 4; ++r) {
        int row = bm + wm + i * 16 + quad * 4 + r;
        int col = bn + wn + j * 16 + lm;
        float v = acc[i][j][r];
        if (BF16_OUT)
          ((u16*)C)[(size_t)row * N + col] = f2b(v);
        else
          ((float*)C)[(size_t)row * N + col] = v;
      }
}

// ---------------- QKV GEMM with fused RoPE/rearrange epilogue v3 (hybrid) -----
__global__ __launch_bounds__(256) void gemm_qkv(const u16* __restrict__ A,
                                                const u16* __restrict__ B,
                                                u16* __restrict__ Qb,
                                                u16* __restrict__ Kb,
                                                u16* __restrict__ VT) {
  constexpr int K = 2048;
  const float SC = 0.12751744f;  // (1/sqrt(128)) * log2(e)
  __shared__ u16 sh[16384];      // As | Bs, reused for V staging
  u16* As = sh;
  u16* Bs = sh + 8192;
  const int tid = threadIdx.x;
  const int wid = tid >> 6;
  const int lane = tid & 63;
  const int lm = lane & 15;
  const int quad = lane >> 4;
  const int r3 = lm & 7;
  const int wm = (wid & 1) * 64;
  const int wn = (wid >> 1) * 64;
  const int bm = blockIdx.y * 128;
  const int bn = blockIdx.x * 128;

  const u16* Ab = A + (size_t)bm * K;
  const u16* Bb = B + (size_t)bn * K;

  f32x4 zero = {0.f, 0.f, 0.f, 0.f};
  f32x4 acc[4][4];
#pragma unroll
  for (int i = 0; i < 4; ++i)
#pragma unroll
    for (int j = 0; j < 4; ++j) acc[i][j] = zero;

  for (int k0 = 0; k0 < K; k0 += 64) {
#pragma unroll
    for (int it = 0; it < 4; ++it) {
      int c = it * 256 + tid;
      int rg = c >> 6, rw = (c >> 3) & 7, u = c & 7;
      int row = rg * 8 + rw;
      int chd = u ^ rw;
      g2l16(Ab + (size_t)row * K + k0 + chd * 8, As + c * 8);
      g2l16(Bb + (size_t)row * K + k0 + chd * 8, Bs + c * 8);
    }
    __syncthreads();
#pragma unroll
    for (int ks = 0; ks < 2; ++ks) {
      bf16x8 a[4], b[4];
      int chd = ks * 4 + quad;
#pragma unroll
      for (int i = 0; i < 4; ++i) {
        int row = wm + i * 16 + lm;
        a[i] = *(const bf16x8*)(As + (((row >> 3) * 64 + r3 * 8 + (chd ^ r3)) * 8));
      }
#pragma unroll
      for (int j = 0; j < 4; ++j) {
        int row = wn + j * 16 + lm;
        b[j] = *(const bf16x8*)(Bs + (((row >> 3) * 64 + r3 * 8 + (chd ^ r3)) * 8));
      }
#pragma unroll
      for (int i = 0; i < 4; ++i)
#pragma unroll
        for (int j = 0; j < 4; ++j)
          acc[i][j] = MFMA32(a[i], b[j], acc[i][j]);
    }
    __syncthreads();
  }

  const int seg = bn >> 10;       // uniform per block
  const int b = bm >> 11;
  const int sbase = bm & 2047;
  const int h = ((bn + wn) >> 6) & 15;  // head for Q/K segments
  const size_t bhQ = (size_t)b * 16 + h;

  if (seg < 2) {
    // ---- sem: direct copy ----
    u16* dst = (seg == 0) ? Qb : Kb;
    const float sc = (seg == 0) ? SC : 1.0f;
#pragma unroll
    for (int i = 0; i < 4; ++i)
#pragma unroll
      for (int r = 0; r < 4; ++r) {
        const int s = sbase + wm + i * 16 + quad * 4 + r;
        u16* base = dst + (bhQ * 2048 + s) * 128;
#pragma unroll
        for (int j = 0; j < 4; ++j) {
          const int d = (wn + j * 16 + lm) & 63;
          base[d] = f2b(acc[i][j][r] * sc);
        }
      }
  } else if (seg < 4) {
    // ---- geo: RoPE in-register, write d in [64,128) ----
    u16* dst = (seg == 2) ? Qb : Kb;
    const float sc = (seg == 2) ? SC : 1.0f;
    const float inv0 = __powf(10000.0f, -(float)(2 * lm) * (1.0f / 64.0f));
    const float inv1 = __powf(10000.0f, -(float)(2 * (16 + lm)) * (1.0f / 64.0f));
#pragma unroll
    for (int i = 0; i < 4; ++i)
#pragma unroll
      for (int r = 0; r < 4; ++r) {
        const int s = sbase + wm + i * 16 + quad * 4 + r;
        float sn0, cs0, sn1, cs1;
        __sincosf((float)s * inv0, &sn0, &cs0);
        __sincosf((float)s * inv1, &sn1, &cs1);
        const float x1a = acc[i][0][r], x2a = acc[i][2][r];  // f0 = lm
        const float x1b = acc[i][1][r], x2b = acc[i][3][r];  // f0 = 16+lm
        u16* base = dst + (bhQ * 2048 + s) * 128 + 64;
        base[lm]      = f2b((x1a * cs0 - x2a * sn0) * sc);
        base[16 + lm] = f2b((x1b * cs1 - x2b * sn1) * sc);
        base[32 + lm] = f2b((x1a * sn0 + x2a * cs0) * sc);
        base[48 + lm] = f2b((x1b * sn1 + x2b * cs1) * sc);
      }
  } else {
    // ---- V: stage TRANSPOSED [d][s] swizzled, write coalesced VT rows -------
    const int hv = (bn - 4096) >> 7;   // one head per tile
    const size_t bh = (size_t)b * 16 + hv;
#pragma unroll
    for (int i = 0; i < 4; ++i)
#pragma unroll
      for (int r = 0; r < 4; ++r) {
        const int sr = wm + i * 16 + quad * 4 + r;
#pragma unroll
        for (int j = 0; j < 4; ++j) {
          const int d = wn + j * 16 + lm;
          sh[d * 128 + (((sr >> 3) ^ (d & 7)) << 3) + (sr & 7)] = f2b(acc[i][j][r]);
        }
      }
    __syncthreads();
#pragma unroll
    for (int it = 0; it < 8; ++it) {
      const int idx = it * 256 + tid;
      const int d = idx >> 4;      // 0..127
      const int ch = idx & 15;     // 8-s chunk
      bf16x8 v = *(const bf16x8*)(sh + d * 128 + ((ch ^ (d & 7)) << 3));
      *(bf16x8*)(VT + (bh * 128 + d) * 2048 + sbase + ch * 8) = v;
    }
  }
}

// ---------------- fused causal attention v10: merged dual-q-tile kt loop ------
// v9 ran q-tiles bx and 31-bx as TWO sequential passes, staging 33 K/V tiles +
// 66 barriers per block. kt<=bx is a subset of kt<=31-bx (bx<=15), so one loop
// over kt=0..31-bx serves both: 24.5 avg stages (-26%), half the barrier pairs,
// same MFMA total -> more compute per barrier. Second P buffer (+9KB): LDS
// 51.2KB x3 blocks = 153.6 < 160 OK. Sequencing keeps one sc[] live at a time.
__global__ __launch_bounds__(256, 3) void attn_v10(const u16* __restrict__ Q,
                                                   const u16* __restrict__ K,
                                                   const u16* __restrict__ VT,
                                                   u16* __restrict__ O) {
  constexpr int S = 2048;
  constexpr int D = 128;
  __shared__ u16 Ks[64 * 128];   // chunk-swizzled
  __shared__ u16 Vs[128 * 64];   // VT tile [d][s_local], chunk-swizzled
  __shared__ u16 PsA[64 * 72];   // wave-private rows; padded stride 72
  __shared__ u16 PsB[64 * 72];
  const int linear = blockIdx.x + (blockIdx.y << 4);
  const int xcd = linear & 7;
  const int slot = linear >> 3;          // 0..63
  const int bh = (xcd << 2) + (slot >> 4);
  const int bx = slot & 15;
  const int b = bh >> 4, h = bh & 15;
  const int tid = threadIdx.x, wid = tid >> 6, lane = tid & 63;
  const int lm = lane & 15, quad = lane >> 4;
  const int rx = lm & 7;
  const int wrow = wid * 16;

  const int qtA = bx;        // 0..15
  const int qtB = 31 - bx;   // 16..31 (always > qtA)

  const u16* Kbh = K + (size_t)bh * S * D;
  const u16* Vbh = VT + (size_t)bh * D * S;

  const bf16x8 vones = {16256, 16256, 16256, 16256, 16256, 16256, 16256, 16256};  // bf16 1.0

  bf16x8 aqA[4], aqB[4];
#pragma unroll
  for (int ks = 0; ks < 4; ++ks) {
    aqA[ks] = *(const bf16x8*)(Q + ((size_t)bh * S + (size_t)qtA * 64 + wrow + lm) * D +
                               ks * 32 + quad * 8);
    aqB[ks] = *(const bf16x8*)(Q + ((size_t)bh * S + (size_t)qtB * 64 + wrow + lm) * D +
                               ks * 32 + quad * 8);
  }

  f32x4 zero = {0.f, 0.f, 0.f, 0.f};
  f32x4 lsumA = zero, lsumB = zero;
  f32x4 oaccA[8], oaccB[8];
#pragma unroll
  for (int t = 0; t < 8; ++t) { oaccA[t] = zero; oaccB[t] = zero; }

#pragma unroll 1
  for (int kt = 0; kt <= qtB; ++kt) {
    __syncthreads();  // prior iteration's readers done with Ks/Vs
    const u16* Kt = Kbh + (size_t)kt * 64 * D;
    const u16* Vt = Vbh + (size_t)kt * 64;
#pragma unroll
    for (int it = 0; it < 4; ++it) {
      int c = it * 256 + tid;
      int row = c >> 4, u = c & 15;
      g2l16(Kt + (size_t)row * 128 + (size_t)(u ^ (row & 7)) * 8, Ks + c * 8);
    }
#pragma unroll
    for (int it = 0; it < 4; ++it) {
      int c = it * 256 + tid;
      int row = c >> 3, u = c & 7;
      g2l16(Vt + (size_t)row * S + (size_t)(u ^ (row & 7)) * 8, Vs + c * 8);
    }
    __syncthreads();  // barrier drains vmcnt: staged data visible

    const bool doA = (kt <= qtA);  // block-uniform

    // ---- QK^T (B) + softmax (B) ----
    {
      f32x4 sc[4];
#pragma unroll
      for (int j = 0; j < 4; ++j) sc[j] = zero;
      __builtin_amdgcn_s_setprio(1);
#pragma unroll
      for (int ks = 0; ks < 4; ++ks) {
        const int kc = ks * 4 + quad;
#pragma unroll
        for (int j = 0; j < 4; ++j) {
          bf16x8 bk = *(const bf16x8*)(Ks + (((j * 16 + lm) * 16 + (kc ^ rx)) * 8));
          sc[j] = MFMA32(aqB[ks], bk, sc[j]);
        }
      }
      __builtin_amdgcn_s_setprio(0);
      const bool diag = (kt == qtB);
#pragma unroll
      for (int r = 0; r < 4; ++r) {
        const int qcol = wrow + quad * 4 + r;
        const int prow = (wrow + quad * 4 + r) * 72;
#pragma unroll
        for (int j = 0; j < 4; ++j) {
          float p = __builtin_amdgcn_exp2f(fminf(sc[j][r], 30.0f));
          if (diag && (j * 16 + lm > qcol)) p = 0.f;
          PsB[prow + j * 16 + lm] = f2b(p);
        }
      }
    }

    // ---- QK^T (A) + softmax (A) ----
    if (doA) {
      f32x4 sc[4];
#pragma unroll
      for (int j = 0; j < 4; ++j) sc[j] = zero;
      __builtin_amdgcn_s_setprio(1);
#pragma unroll
      for (int ks = 0; ks < 4; ++ks) {
        const int kc = ks * 4 + quad;
#pragma unroll
        for (int j = 0; j < 4; ++j) {
          bf16x8 bk = *(const bf16x8*)(Ks + (((j * 16 + lm) * 16 + (kc ^ rx)) * 8));
          sc[j] = MFMA32(aqA[ks], bk, sc[j]);
        }
      }
      __builtin_amdgcn_s_setprio(0);
      const bool diag = (kt == qtA);
#pragma unroll
      for (int r = 0; r < 4; ++r) {
        const int qcol = wrow + quad * 4 + r;
        const int prow = (wrow + quad * 4 + r) * 72;
#pragma unroll
        for (int j = 0; j < 4; ++j) {
          float p = __builtin_amdgcn_exp2f(fminf(sc[j][r], 30.0f));
          if (diag && (j * 16 + lm > qcol)) p = 0.f;
          PsA[prow + j * 16 + lm] = f2b(p);
        }
      }
    }
    // no barrier: Ps rows are wave-private (proven R4)

    // ---- PV (B) ----
    __builtin_amdgcn_s_setprio(1);
#pragma unroll
    for (int ks = 0; ks < 2; ++ks) {
      bf16x8 ap = *(const bf16x8*)(PsB + (wrow + lm) * 72 + ks * 32 + quad * 8);
      const int kc = ks * 4 + quad;
      lsumB = MFMA32(ap, vones, lsumB);
#pragma unroll
      for (int t = 0; t < 8; ++t) {
        bf16x8 bv = *(const bf16x8*)(Vs + (((t * 16 + lm) * 8 + (kc ^ rx)) * 8));
        oaccB[t] = MFMA32(ap, bv, oaccB[t]);
      }
    }
    __builtin_amdgcn_s_setprio(0);

    // ---- PV (A) ----
    if (doA) {
      __builtin_amdgcn_s_setprio(1);
#pragma unroll
      for (int ks = 0; ks < 2; ++ks) {
        bf16x8 ap = *(const bf16x8*)(PsA + (wrow + lm) * 72 + ks * 32 + quad * 8);
        const int kc = ks * 4 + quad;
        lsumA = MFMA32(ap, vones, lsumA);
#pragma unroll
        for (int t = 0; t < 8; ++t) {
          bf16x8 bv = *(const bf16x8*)(Vs + (((t * 16 + lm) * 8 + (kc ^ rx)) * 8));
          oaccA[t] = MFMA32(ap, bv, oaccA[t]);
        }
      }
      __builtin_amdgcn_s_setprio(0);
    }
  }

  // epilogues
#pragma unroll
  for (int r = 0; r < 4; ++r) {
    const int rr = quad * 4 + r;
    {
      float inv = 1.0f / lsumA[r];
      const int srow = qtA * 64 + wrow + rr;
      u16* Orow = O + ((size_t)b * S + srow) * 2048 + h * 128;
#pragma unroll
      for (int t = 0; t < 8; ++t) Orow[t * 16 + lm] = f2b(oaccA[t][r] * inv);
    }
    {
      float inv = 1.0f / lsumB[r];
      const int srow = qtB * 64 + wrow + rr;
      u16* Orow = O + ((size_t)b * S + srow) * 2048 + h * 128;
#pragma unroll
      for (int t = 0; t < 8; ++t) Orow[t * 16 + lm] = f2b(oaccB[t][r] * inv);
    }
  }
}

extern "C" void kernel_launch(void* const* d_in, const int* in_sizes, int n_in,
                              void* d_out, int out_size, void* d_ws, size_t ws_size,
                              hipStream_t stream) {
  const float* x      = (const float*)d_in[0];
  const float* Wq_sem = (const float*)d_in[1];
  const float* Wk_sem = (const float*)d_in[2];
  const float* Wq_geo = (const float*)d_in[3];
  const float* Wk_geo = (const float*)d_in[4];
  const float* Wv     = (const float*)d_in[5];
  const float* Wo     = (const float*)d_in[6];

  char* ws = (char*)d_ws;
  // layout (bytes):
  //   [0, 16M)          xb  (x bf16, 4096x2048)
  //   [16M, 41.2M)      Wall (6144x2048 bf16)   -> later reused as O
  //   [41.2M, 49.6M)    Wob  (2048x2048 bf16)
  //   [49.6M, 66.3M)    Qb   (bf16, 32 heads x 2048 x 128)
  // d_out (33.5MB) used as scratch for K (16.7M) + VT (16.7M) until final GEMM.
  u16* xb   = (u16*)(ws);
  u16* Wall = (u16*)(ws + 16777216);
  u16* Wob  = (u16*)(ws + 16777216 + 25165824);
  u16* Qb   = (u16*)(ws + 16777216 + 25165824 + 8388608);
  u16* Ob   = Wall;
  u16* Kb   = (u16*)d_out;
  u16* VT   = (u16*)((char*)d_out + 16777216);

  // all casts in one launch
  cast_all<<<24576, 256, 0, stream>>>(x, Wq_sem, Wk_sem, Wq_geo, Wk_geo, Wv, Wo,
                                      xb, Wall, Wob);

  // fused QKV projection + RoPE + head rearrange: writes Q/K/VT directly
  gemm_qkv<<<dim3(48, 32), 256, 0, stream>>>(xb, Wall, Qb, Kb, VT);

  // causal flash attention -> O (B*S, 2048) bf16
  attn_v10<<<dim3(16, 32), 256, 0, stream>>>(Qb, Kb, VT, Ob);

  // final projection: out = O @ Wo^T  (M=4096, N=2048, K=2048), fp32 out
  gemm_bt<false><<<dim3(16, 32), 256, 0, stream>>>(Ob, Wob, d_out, 2048, 2048);
}